// Round 10
// baseline (1644.476 us; speedup 1.0000x reference)
//
#include <hip/hip_runtime.h>
#include <hip/hip_bf16.h>
#include <math.h>

#define D_MODEL 2816
#define DM4 704          // D_MODEL/4
#define D_DENSE 2112
#define N_EXPERTS 128
#define D_FFN 704
#define DF4 176          // D_FFN/4
#define TOPK 8
#define H 16
#define DH 256
#define NKV 8
#define MAX_CTX 4096
#define EPS 1e-6f

__device__ __forceinline__ float wsum(float v){
  #pragma unroll
  for(int o=32;o>0;o>>=1) v += __shfl_down(v, o, 64);
  return v;
}
__device__ __forceinline__ float wmax(float v){
  #pragma unroll
  for(int o=32;o>0;o>>=1) v = fmaxf(v, __shfl_down(v, o, 64));
  return v;
}
__device__ __forceinline__ float wsum_all(float v){
  #pragma unroll
  for(int o=32;o>0;o>>=1) v += __shfl_xor(v, o, 64);
  return v;
}
__device__ __forceinline__ float wmax_all(float v){
  #pragma unroll
  for(int o=32;o>0;o>>=1) v = fmaxf(v, __shfl_xor(v, o, 64));
  return v;
}
__device__ __forceinline__ int wmin_all_i(int v){
  #pragma unroll
  for(int o=32;o>0;o>>=1) v = min(v, __shfl_xor(v, o, 64));
  return v;
}
__device__ __forceinline__ float block_sum(float v, float* sm){
  int lane = threadIdx.x & 63, w = threadIdx.x >> 6;
  int nw = blockDim.x >> 6;
  v = wsum(v);
  __syncthreads();
  if (lane == 0) sm[w] = v;
  __syncthreads();
  float t = 0.f;
  for (int i = 0; i < nw; i++) t += sm[i];
  return t;
}
__device__ __forceinline__ float gelu_tanh(float x){
  float x3 = x*x*x;
  return 0.5f*x*(1.f + tanhf(0.7978845608028654f*(x + 0.044715f*x3)));
}
__device__ __forceinline__ float dot4(float4 a, float4 b){
  return fmaf(a.x,b.x, fmaf(a.y,b.y, fmaf(a.z,b.z, a.w*b.w)));
}

// ---- batched-load row-dot: issue ALL loads, then FMA ----
__device__ __forceinline__ float dotrow704(const float4* __restrict__ wr,
    const float4* __restrict__ xs, int lane){
  float4 w[11];
  #pragma unroll
  for (int i=0;i<11;i++) w[i] = wr[lane + 64*i];
  float acc = 0.f;
  #pragma unroll
  for (int i=0;i<11;i++) acc += dot4(w[i], xs[lane + 64*i]);
  return wsum(acc);
}

// K1: fused rmsnorm(x) + q/k/v GEMV (batched loads)
__global__ __launch_bounds__(256) void k_qkv(const float* __restrict__ Wq,
    const float* __restrict__ Wk, const float* __restrict__ Wv,
    const float* __restrict__ x, const float* __restrict__ lw,
    float* __restrict__ out){
  __shared__ float sh[D_MODEL];
  __shared__ float sm[8];
  int t = threadIdx.x;
  float xv[11]; float ss = 0.f;
  #pragma unroll
  for (int i=0;i<11;i++){ xv[i] = x[t + 256*i]; ss += xv[i]*xv[i]; }
  ss = block_sum(ss, sm);
  float r = rsqrtf(ss/(float)D_MODEL + EPS);
  #pragma unroll
  for (int i=0;i<11;i++){ int idx=t+256*i; sh[idx] = xv[i]*r*(1.f+lw[idx]); }
  __syncthreads();

  int row = blockIdx.x*4 + (t>>6);
  int lane = t & 63;
  const float* W; int rr;
  if (row < 4096){ W=Wq; rr=row; }
  else if (row < 6144){ W=Wk; rr=row-4096; }
  else { W=Wv; rr=row-6144; }
  float acc = dotrow704((const float4*)(W + (size_t)rr*D_MODEL),
                        (const float4*)sh, lane);
  if (lane==0) out[row]=acc;
}

// K2: per-head rmsnorm (+weight for q,k) then RoPE for q,k; plain rmsnorm for v
__global__ __launch_bounds__(256) void k_headnorm(const float* __restrict__ qkv,
    const float* __restrict__ qw, const float* __restrict__ kw,
    const float* __restrict__ cs, const float* __restrict__ sn,
    float* __restrict__ qf, float* __restrict__ kf, float* __restrict__ vf){
  __shared__ float sm[8];
  __shared__ float nb[DH];
  int b = blockIdx.x, t = threadIdx.x;
  const float* src; float* dst; const float* w = nullptr; bool rope=false;
  if (b < 16){ src=qkv + b*DH; dst=qf + b*DH; w=qw; rope=true; }
  else if (b < 24){ int hh=b-16; src=qkv+4096+hh*DH; dst=kf+hh*DH; w=kw; rope=true; }
  else { int hh=b-24; src=qkv+6144+hh*DH; dst=vf+hh*DH; }
  float v = src[t];
  float ss = block_sum(v*v, sm);
  float r = rsqrtf(ss/(float)DH + EPS);
  float nv = v*r*(w ? (1.f+w[t]) : 1.f);
  nb[t]=nv;
  __syncthreads();
  float o = nv;
  if (rope){
    float rot = (t < 128) ? -nb[t+128] : nb[t-128];
    o = nv*cs[t] + rot*sn[t];
  }
  dst[t]=o;
}

// K3: attn partials (blocks 0..255) + contiguous KV copy (256..2303)
#define TOT4 (NKV*MAX_CTX*(DH/4))   // 2,097,152 float4 per tensor
__global__ __launch_bounds__(256) void k_kvattn(const float* __restrict__ kc,
    const float* __restrict__ vc, const float* __restrict__ kf,
    const float* __restrict__ vf, const float* __restrict__ qf,
    const float* __restrict__ wm, const float* __restrict__ mask,
    float* __restrict__ ko, float* __restrict__ vo, float* __restrict__ part){
  int bid = blockIdx.x;
  int t = threadIdx.x;
  if (bid >= 256){
    size_t base = (size_t)(bid - 256) * 2048;
    int tensor = base >= (size_t)TOT4;
    size_t j0 = base - (tensor ? (size_t)TOT4 : 0);
    int head = (int)(j0 >> 18);
    const float4* cache = (const float4*)(tensor ? vc : kc) + j0;
    float4* outp = (float4*)(tensor ? vo : ko) + j0;
    const float4* a4 = (const float4*)((tensor ? vf : kf) + head*DH);
    float4 c[8]; float4 aq[8]; float mq[8];
    #pragma unroll
    for (int q=0;q<8;q++) c[q] = cache[q*256 + t];
    #pragma unroll
    for (int q=0;q<8;q++){
      size_t j = j0 + q*256 + t;
      aq[q] = a4[j & 63];
      mq[q] = wm[(j >> 6) & (MAX_CTX-1)];
    }
    #pragma unroll
    for (int q=0;q<8;q++){
      c[q].x = fmaf(aq[q].x, mq[q], c[q].x);
      c[q].y = fmaf(aq[q].y, mq[q], c[q].y);
      c[q].z = fmaf(aq[q].z, mq[q], c[q].z);
      c[q].w = fmaf(aq[q].w, mq[q], c[q].w);
      outp[q*256 + t] = c[q];
    }
    return;
  }
  __shared__ float sc[256];
  __shared__ float sw[256];
  __shared__ float sm[8];
  int head = bid >> 4, chunk = bid & 15;
  int kvh = head >> 1;
  int lane = t & 63, wv = t >> 6;
  int base = chunk*256;
  float mk_t = mask[base + t];
  float live = block_sum((mk_t > -1e8f) ? 1.f : 0.f, sm);
  float* p = part + (size_t)(head*16+chunk)*258;
  if (live == 0.f){
    if (t == 0){ p[0] = -3.0e38f; p[1] = 0.f; }
    return;
  }
  float4 q  = ((const float4*)(qf + head*DH))[lane];
  float4 kp = ((const float4*)(kf + kvh*DH))[lane];
  float vp  = vf[kvh*DH + t];
  const float* K = kc + (size_t)kvh*MAX_CTX*DH;
  const float* V = vc + (size_t)kvh*MAX_CTX*DH;
  for (int i=0;i<64;i++){
    int pp = wv*64 + i;
    int pos = base + pp;
    float mk = mask[pos];
    float s = -3.0e38f;
    if (mk > -1e8f){
      float m = wm[pos];
      float4 kv = ((const float4*)(K + (size_t)pos*DH))[lane];
      kv.x = fmaf(kp.x, m, kv.x); kv.y = fmaf(kp.y, m, kv.y);
      kv.z = fmaf(kp.z, m, kv.z); kv.w = fmaf(kp.w, m, kv.w);
      float d = wsum(dot4(q, kv));
      s = d + mk;
    }
    if (lane==0) sc[pp] = s;
  }
  __syncthreads();
  float sv = sc[t];
  float mx = wmax(sv);
  __syncthreads();
  if (lane==0) sm[wv]=mx;
  __syncthreads();
  mx = fmaxf(fmaxf(sm[0],sm[1]),fmaxf(sm[2],sm[3]));
  float w = (sv > -1e30f) ? __expf(sv - mx) : 0.f;
  sw[t] = w;
  float ssum = block_sum(w, sm);
  float acc = 0.f;
  for (int i=0;i<256;i++){
    float wi = sw[i];
    if (wi != 0.f){
      float v = fmaf(vp, wm[base+i], V[(size_t)(base+i)*DH + t]);
      acc = fmaf(wi, v, acc);
    }
  }
  if (t==0){ p[0]=mx; p[1]=ssum; }
  p[2+t]=acc;
}

// K4: combine partials -> ctx
__global__ __launch_bounds__(256) void k_attn_comb(const float* __restrict__ part,
    float* __restrict__ ctx){
  int head = blockIdx.x, t = threadIdx.x;
  float M = -3.0e38f;
  for (int c=0;c<16;c++) M = fmaxf(M, part[(size_t)(head*16+c)*258]);
  float tot = 0.f, acc = 0.f;
  for (int c=0;c<16;c++){
    const float* p = part + (size_t)(head*16+c)*258;
    float mc=p[0], scv=p[1];
    if (scv > 0.f){
      float f = __expf(mc - M);
      tot = fmaf(scv, f, tot);
      acc = fmaf(f, p[2+t], acc);
    }
  }
  ctx[head*DH + t] = acc / tot;
}

// K5: Wo GEMV, ctx staged in LDS, 16 batched loads
__global__ __launch_bounds__(256) void k_wo(const float* __restrict__ Wo,
    const float* __restrict__ ctxv, float* __restrict__ a){
  __shared__ float4 xs[1024];
  int t = threadIdx.x;
  #pragma unroll
  for (int i=0;i<4;i++) xs[t + 256*i] = ((const float4*)ctxv)[t + 256*i];
  __syncthreads();
  int row = blockIdx.x*4 + (t>>6);
  int lane = t & 63;
  const float4* wr = (const float4*)(Wo + (size_t)row*(H*DH));
  float4 w[16];
  #pragma unroll
  for (int i=0;i<16;i++) w[i] = wr[lane + 64*i];
  float acc = 0.f;
  #pragma unroll
  for (int i=0;i<16;i++) acc += dot4(w[i], xs[lane + 64*i]);
  acc = wsum(acc);
  if (lane==0) a[row]=acc;
}

// K6: x1 = x + rmsnorm(a, post_attn); pre/hr/pre2 = the three norms of x1
__global__ __launch_bounds__(256) void k_postattn(const float* __restrict__ a,
    const float* __restrict__ x, const float* __restrict__ wpost,
    const float* __restrict__ wpre, const float* __restrict__ rscale,
    const float* __restrict__ wpre2,
    float* __restrict__ x1, float* __restrict__ pre,
    float* __restrict__ hr, float* __restrict__ pre2){
  __shared__ float sm[8];
  int t = threadIdx.x;
  float av[11]; float ss=0.f;
  #pragma unroll
  for (int i=0;i<11;i++){ av[i]=a[t+256*i]; ss += av[i]*av[i]; }
  ss = block_sum(ss, sm);
  float ra = rsqrtf(ss/(float)D_MODEL + EPS);
  float xv[11]; float ss2=0.f;
  #pragma unroll
  for (int i=0;i<11;i++){
    int idx=t+256*i;
    xv[i] = x[idx] + av[i]*ra*(1.f+wpost[idx]);
    ss2 += xv[i]*xv[i];
  }
  ss2 = block_sum(ss2, sm);
  float r1 = rsqrtf(ss2/(float)D_MODEL + EPS);
  const float invsq = rsqrtf((float)D_MODEL);
  #pragma unroll
  for (int i=0;i<11;i++){
    int idx=t+256*i;
    float n = xv[i]*r1;
    x1[idx]=xv[i];
    pre[idx]=n*(1.f+wpre[idx]);
    hr[idx]=n*rscale[idx]*invsq;
    pre2[idx]=n*(1.f+wpre2[idx]);
  }
}

// K7: dense gate/up (0..527) + router logits (528..559)
__global__ __launch_bounds__(256) void k_dense_gu_router(const float* __restrict__ Wg,
    const float* __restrict__ Wu, const float* __restrict__ pre,
    const float* __restrict__ Wp, const float* __restrict__ hr,
    float* __restrict__ act, float* __restrict__ lg){
  __shared__ float4 xs[DM4];
  int t = threadIdx.x;
  int lane = t & 63, wv = t >> 6;
  bool isdense = (blockIdx.x < 528);
  const float4* src = (const float4*)(isdense ? pre : hr);
  xs[t] = src[t];
  xs[t+256] = src[t+256];
  if (t < 192) xs[t+512] = src[t+512];
  __syncthreads();
  if (isdense){
    int row = blockIdx.x*4 + wv;
    const float4* g4 = (const float4*)(Wg + (size_t)row*D_MODEL);
    const float4* u4 = (const float4*)(Wu + (size_t)row*D_MODEL);
    float4 g[11], u[11];
    #pragma unroll
    for (int i=0;i<11;i++) g[i] = g4[lane + 64*i];
    #pragma unroll
    for (int i=0;i<11;i++) u[i] = u4[lane + 64*i];
    float ag=0.f, au=0.f;
    #pragma unroll
    for (int i=0;i<11;i++){
      float4 b = xs[lane + 64*i];
      ag += dot4(g[i], b);
      au += dot4(u[i], b);
    }
    ag = wsum(ag); au = wsum(au);
    if (lane==0) act[row] = gelu_tanh(ag)*au;
  } else {
    int row = (blockIdx.x-528)*4 + wv;
    float acc = dotrow704((const float4*)(Wp + (size_t)row*D_MODEL), xs, lane);
    if (lane==0) lg[row]=acc;
  }
}

// K8: softmax + top-8 (1 wave)
__global__ __launch_bounds__(64) void k_topk(const float* __restrict__ lg,
    const float* __restrict__ pes, float* __restrict__ selw, int* __restrict__ seli){
  int lane = threadIdx.x;
  float l0 = lg[lane], l1 = lg[lane+64];
  float m = wmax_all(fmaxf(l0,l1));
  float e0 = __expf(l0-m), e1 = __expf(l1-m);
  float s = wsum_all(e0+e1);
  float p0 = e0/s, p1 = e1/s;
  float vals[8]; int idxs[8]; float tw=0.f;
  #pragma unroll
  for (int ts=0;ts<8;ts++){
    float mx = wmax_all(fmaxf(p0,p1));
    int cand = 0x7fffffff;
    if (p0 == mx) cand = lane;
    else if (p1 == mx) cand = lane + 64;
    int imin = wmin_all_i(cand);
    if (imin == lane) p0 = -1.f;
    else if (imin == lane+64) p1 = -1.f;
    vals[ts]=mx; idxs[ts]=imin; tw += mx;
  }
  if (lane == 0){
    #pragma unroll
    for (int ts=0;ts<8;ts++){
      selw[ts] = vals[ts]/tw*pes[idxs[ts]];
      seli[ts] = idxs[ts];
    }
  }
}

// K9: dense down-proj (0..703) + MoE gate/up (704..2111)
__global__ __launch_bounds__(256) void k_ddown_moegu(const float* __restrict__ Wd,
    const float* __restrict__ act, float* __restrict__ dense,
    const float* __restrict__ pWg, const float* __restrict__ pWu,
    const float* __restrict__ pre2, const int* __restrict__ seli,
    float* __restrict__ hh){
  __shared__ float4 xs[DM4];
  int t = threadIdx.x;
  int lane = t & 63, wv = t >> 6;
  if (blockIdx.x < 704){
    xs[t] = ((const float4*)act)[t];
    xs[t+256] = ((const float4*)act)[t+256];
    if (t < 16) xs[t+512] = ((const float4*)act)[t+512];
    __syncthreads();
    int row = blockIdx.x*4 + wv;
    const float4* wr = (const float4*)(Wd + (size_t)row*D_DENSE);
    float4 w[8];
    #pragma unroll
    for (int i=0;i<8;i++) w[i] = wr[lane + 64*i];
    float4 w8 = (lane < 16) ? wr[lane + 512] : make_float4(0.f,0.f,0.f,0.f);
    float acc = 0.f;
    #pragma unroll
    for (int i=0;i<8;i++) acc += dot4(w[i], xs[lane + 64*i]);
    if (lane < 16) acc += dot4(w8, xs[lane + 512]);
    acc = wsum(acc);
    if (lane==0) dense[row]=acc;
  } else {
    xs[t] = ((const float4*)pre2)[t];
    xs[t+256] = ((const float4*)pre2)[t+256];
    if (t < 192) xs[t+512] = ((const float4*)pre2)[t+512];
    __syncthreads();
    int gidx = (blockIdx.x-704)*4 + wv;
    int sl = gidx / D_FFN;
    int f = gidx - sl*D_FFN;
    int e = seli[sl];
    int p = e >> 4, g = e & 15;
    size_t ro = ((size_t)p*(16*D_FFN) + (size_t)g*D_FFN + f)*D_MODEL;
    const float4* g4 = (const float4*)(pWg + ro);
    const float4* u4 = (const float4*)(pWu + ro);
    float4 gw[11], uw[11];
    #pragma unroll
    for (int i=0;i<11;i++) gw[i] = g4[lane + 64*i];
    #pragma unroll
    for (int i=0;i<11;i++) uw[i] = u4[lane + 64*i];
    float ag=0.f, au=0.f;
    #pragma unroll
    for (int i=0;i<11;i++){
      float4 b = xs[lane + 64*i];
      ag += dot4(gw[i], b);
      au += dot4(uw[i], b);
    }
    ag = wsum(ag); au = wsum(au);
    if (lane==0) hh[sl*D_FFN + f] = gelu_tanh(ag)*au;
  }
}

// K10: MoE down-proj
__global__ __launch_bounds__(256) void k_moe_down(const float* __restrict__ Wd,
    const float* __restrict__ hh, const int* __restrict__ seli,
    float* __restrict__ pere){
  __shared__ float4 xs[DF4];
  int t = threadIdx.x;
  int gidx = blockIdx.x*4 + (t>>6);
  int lane = t & 63;
  int sl = gidx / D_MODEL;
  int d = gidx - sl*D_MODEL;
  if (t < DF4) xs[t] = ((const float4*)(hh + sl*D_FFN))[t];
  __syncthreads();
  int e = seli[sl];
  int p = e >> 4, g = e & 15;
  const float4* wr = (const float4*)(Wd + ((size_t)p*(16*D_MODEL) + (size_t)g*D_MODEL + d)*D_FFN);
  float4 w0 = wr[lane];
  float4 w1 = wr[lane + 64];
  float4 w2 = (lane < 48) ? wr[lane + 128] : make_float4(0.f,0.f,0.f,0.f);
  float acc = dot4(w0, xs[lane]) + dot4(w1, xs[lane + 64]);
  if (lane < 48) acc += dot4(w2, xs[lane + 128]);
  acc = wsum(acc);
  if (lane==0) pere[sl*D_MODEL + d] = acc;
}

// K11: final combine
__global__ __launch_bounds__(256) void k_final(const float* __restrict__ pere,
    const float* __restrict__ selw, const float* __restrict__ dense,
    const float* __restrict__ x1, const float* __restrict__ w2,
    const float* __restrict__ w1, const float* __restrict__ wf,
    const float* __restrict__ lsc, float* __restrict__ out){
  __shared__ float sm[8];
  int t = threadIdx.x;
  float mo[11], dn[11]; float ssm_=0.f, ssd=0.f;
  #pragma unroll
  for (int i=0;i<11;i++){
    int idx=t+256*i;
    float mv=0.f;
    #pragma unroll
    for (int s=0;s<TOPK;s++) mv = fmaf(selw[s], pere[s*D_MODEL+idx], mv);
    mo[i]=mv; ssm_ += mv*mv;
    dn[i]=dense[idx]; ssd += dn[i]*dn[i];
  }
  ssm_ = block_sum(ssm_, sm);
  ssd = block_sum(ssd, sm);
  float rm = rsqrtf(ssm_/(float)D_MODEL + EPS);
  float rd = rsqrtf(ssd/(float)D_MODEL + EPS);
  float tv[11]; float sst=0.f;
  #pragma unroll
  for (int i=0;i<11;i++){
    int idx=t+256*i;
    float h2 = mo[i]*rm*(1.f+w2[idx]);
    float h1 = dn[i]*rd*(1.f+w1[idx]);
    tv[i]=h1+h2; sst += tv[i]*tv[i];
  }
  sst = block_sum(sst, sm);
  float rt = rsqrtf(sst/(float)D_MODEL + EPS);
  float l = lsc[0];
  #pragma unroll
  for (int i=0;i<11;i++){
    int idx=t+256*i;
    out[idx] = (x1[idx] + tv[i]*rt*(1.f+wf[idx]))*l;
  }
}

// ===== PROBE A: exact production GEMV pattern, 4.06 GB (>L3), wave-per-row ====
__global__ __launch_bounds__(256) void k_probe_gemv(const float* __restrict__ Wa,
    const float* __restrict__ Wb, const float* __restrict__ xsrc,
    float* __restrict__ sink){
  __shared__ float4 xs[DM4];
  int t = threadIdx.x;
  xs[t] = ((const float4*)xsrc)[t];
  xs[t+256] = ((const float4*)xsrc)[t+256];
  if (t < 192) xs[t+512] = ((const float4*)xsrc)[t+512];
  __syncthreads();
  int lane = t & 63;
  int wid = blockIdx.x*4 + (t>>6);           // 0..8191
  float acc = 0.f;
  for (int pass=0; pass<2; ++pass){
    for (int r = wid; r < 90112; r += 8192){ // 90112 rows x 11264B per matrix
      acc += dotrow704((const float4*)(Wa + (size_t)r*D_MODEL), xs, lane);
      acc += dotrow704((const float4*)(Wb + (size_t)r*D_MODEL), xs, lane);
    }
  }
  if (lane==0) sink[wid] = acc;
}

// ===== PROBE B: linear grid-stride float4 read of the same 4.06 GB ===========
__global__ __launch_bounds__(256) void k_probe_lin(const float* __restrict__ Wa,
    const float* __restrict__ Wb, float* __restrict__ sink){
  const size_t N4 = (size_t)90112 * DM4;
  int t = threadIdx.x;
  int lane = t & 63;
  float acc = 0.f;
  const size_t stride = (size_t)2048 * 256;
  for (int pass=0; pass<2; ++pass){
    for (size_t i = (size_t)blockIdx.x*256 + t; i < N4; i += stride){
      float4 a = ((const float4*)Wa)[i];
      float4 b = ((const float4*)Wb)[i];
      acc += (a.x+a.y+a.z+a.w) + (b.x+b.y+b.z+b.w);
    }
  }
  acc = wsum(acc);
  if (lane==0) sink[blockIdx.x*4 + (t>>6)] = acc;
}

extern "C" void kernel_launch(void* const* d_in, const int* in_sizes, int n_in,
                              void* d_out, int out_size, void* d_ws, size_t ws_size,
                              hipStream_t stream){
  const float* x        = (const float*)d_in[0];
  const float* cs       = (const float*)d_in[1];
  const float* sn       = (const float*)d_in[2];
  const float* kc       = (const float*)d_in[3];
  const float* vc       = (const float*)d_in[4];
  const float* mask     = (const float*)d_in[5];
  const float* wm       = (const float*)d_in[6];
  const float* in_ln    = (const float*)d_in[7];
  const float* post_attn= (const float*)d_in[8];
  const float* pre_ffn  = (const float*)d_in[9];
  const float* post_ffn1= (const float*)d_in[10];
  const float* pre_ffn2 = (const float*)d_in[11];
  const float* post_ffn2= (const float*)d_in[12];
  const float* post_ffn = (const float*)d_in[13];
  const float* Wq       = (const float*)d_in[14];
  const float* Wk       = (const float*)d_in[15];
  const float* Wv       = (const float*)d_in[16];
  const float* Wo       = (const float*)d_in[17];
  const float* qnw      = (const float*)d_in[18];
  const float* knw      = (const float*)d_in[19];
  const float* dWg      = (const float*)d_in[20];
  const float* dWu      = (const float*)d_in[21];
  const float* dWd      = (const float*)d_in[22];
  const float* rWp      = (const float*)d_in[23];
  const float* rscale   = (const float*)d_in[24];
  const float* rpes     = (const float*)d_in[25];
  const float* pWg      = (const float*)d_in[26];
  const float* pWu      = (const float*)d_in[27];
  const float* pWd      = (const float*)d_in[28];
  const float* lsc      = (const float*)d_in[29];

  float* out = (float*)d_out;
  float* ko  = out + D_MODEL;
  float* vo  = ko + (size_t)NKV*MAX_CTX*DH;

  float* ws   = (float*)d_ws;
  float* qkv  = ws + 0;        // 8192
  float* qf   = ws + 8192;     // 4096
  float* kf   = ws + 12288;    // 2048
  float* vf   = ws + 14336;    // 2048
  float* ctx  = ws + 16384;    // 4096
  float* a    = ws + 20480;    // 2816
  float* x1   = ws + 23296;    // 2816
  float* pre  = ws + 26112;    // 2816
  float* hr   = ws + 28928;    // 2816
  float* pre2 = ws + 31744;    // 2816
  float* act  = ws + 34560;    // 2112
  float* dense= ws + 36672;    // 2816
  float* lg   = ws + 39488;    // 128
  float* selw = ws + 39616;    // 8
  int*   seli = (int*)(ws + 39624); // 8
  float* hh   = ws + 39632;    // 8*704 = 5632
  float* pere = ws + 45264;    // 8*2816 = 22528
  float* part = ws + 67792;    // 16*16*258 = 66048
  float* psA  = ws + 133840;   // 8192 probe sink A
  float* psB  = ws + 142032;   // 8192 probe sink B

  k_qkv            <<<2048, 256, 0, stream>>>(Wq, Wk, Wv, x, in_ln, qkv);
  k_headnorm       <<<32,   256, 0, stream>>>(qkv, qnw, knw, cs, sn, qf, kf, vf);
  k_kvattn         <<<2304, 256, 0, stream>>>(kc, vc, kf, vf, qf, wm, mask, ko, vo, part);
  k_attn_comb      <<<16,   256, 0, stream>>>(part, ctx);
  k_wo             <<<704,  256, 0, stream>>>(Wo, ctx, a);
  k_postattn       <<<1,    256, 0, stream>>>(a, x, post_attn, pre_ffn, rscale, pre_ffn2,
                                              x1, pre, hr, pre2);
  k_dense_gu_router<<<560,  256, 0, stream>>>(dWg, dWu, pre, rWp, hr, act, lg);
  k_topk           <<<1,     64, 0, stream>>>(lg, rpes, selw, seli);
  k_ddown_moegu    <<<2112, 256, 0, stream>>>(dWd, act, dense, pWg, pWu, pre2, seli, hh);
  k_moe_down       <<<5632, 256, 0, stream>>>(pWd, hh, seli, pere);
  k_final          <<<1,    256, 0, stream>>>(pere, selw, dense, x1,
                                              post_ffn2, post_ffn1, post_ffn, lsc, out);

  // ---- PROBES (no deps on outputs; write only dead scratch) ----
  k_probe_gemv     <<<2048, 256, 0, stream>>>(pWg, pWu, pre2, psA);
  k_probe_lin      <<<2048, 256, 0, stream>>>(pWg, pWu, psB);
}

// Round 11
// 239.297 us; speedup vs baseline: 6.8721x; 6.8721x over previous
//
#include <hip/hip_runtime.h>
#include <hip/hip_bf16.h>
#include <math.h>

#define D_MODEL 2816
#define DM4 704          // D_MODEL/4
#define D_DENSE 2112
#define N_EXPERTS 128
#define D_FFN 704
#define DF4 176          // D_FFN/4
#define TOPK 8
#define H 16
#define DH 256
#define NKV 8
#define MAX_CTX 4096
#define EPS 1e-6f

__device__ __forceinline__ float wsum(float v){
  #pragma unroll
  for(int o=32;o>0;o>>=1) v += __shfl_down(v, o, 64);
  return v;
}
__device__ __forceinline__ float wmax(float v){
  #pragma unroll
  for(int o=32;o>0;o>>=1) v = fmaxf(v, __shfl_down(v, o, 64));
  return v;
}
__device__ __forceinline__ float wsum_all(float v){
  #pragma unroll
  for(int o=32;o>0;o>>=1) v += __shfl_xor(v, o, 64);
  return v;
}
__device__ __forceinline__ float wmax_all(float v){
  #pragma unroll
  for(int o=32;o>0;o>>=1) v = fmaxf(v, __shfl_xor(v, o, 64));
  return v;
}
__device__ __forceinline__ int wmin_all_i(int v){
  #pragma unroll
  for(int o=32;o>0;o>>=1) v = min(v, __shfl_xor(v, o, 64));
  return v;
}
__device__ __forceinline__ float block_sum(float v, float* sm){
  int lane = threadIdx.x & 63, w = threadIdx.x >> 6;
  int nw = blockDim.x >> 6;
  v = wsum(v);
  __syncthreads();
  if (lane == 0) sm[w] = v;
  __syncthreads();
  float t = 0.f;
  for (int i = 0; i < nw; i++) t += sm[i];
  return t;
}
__device__ __forceinline__ float gelu_tanh(float x){
  float x3 = x*x*x;
  return 0.5f*x*(1.f + tanhf(0.7978845608028654f*(x + 0.044715f*x3)));
}
__device__ __forceinline__ float dot4(float4 a, float4 b){
  return fmaf(a.x,b.x, fmaf(a.y,b.y, fmaf(a.z,b.z, a.w*b.w)));
}

// ---- batched-load row-dot: issue ALL loads, then FMA ----
__device__ __forceinline__ float dotrow704(const float4* __restrict__ wr,
    const float4* __restrict__ xs, int lane){
  float4 w[11];
  #pragma unroll
  for (int i=0;i<11;i++) w[i] = wr[lane + 64*i];
  float acc = 0.f;
  #pragma unroll
  for (int i=0;i<11;i++) acc += dot4(w[i], xs[lane + 64*i]);
  return wsum(acc);
}

// K1: fused rmsnorm(x) + q/k/v GEMV (batched loads)
__global__ __launch_bounds__(256) void k_qkv(const float* __restrict__ Wq,
    const float* __restrict__ Wk, const float* __restrict__ Wv,
    const float* __restrict__ x, const float* __restrict__ lw,
    float* __restrict__ out){
  __shared__ float sh[D_MODEL];
  __shared__ float sm[8];
  int t = threadIdx.x;
  float xv[11]; float ss = 0.f;
  #pragma unroll
  for (int i=0;i<11;i++){ xv[i] = x[t + 256*i]; ss += xv[i]*xv[i]; }
  ss = block_sum(ss, sm);
  float r = rsqrtf(ss/(float)D_MODEL + EPS);
  #pragma unroll
  for (int i=0;i<11;i++){ int idx=t+256*i; sh[idx] = xv[i]*r*(1.f+lw[idx]); }
  __syncthreads();

  int row = blockIdx.x*4 + (t>>6);
  int lane = t & 63;
  const float* W; int rr;
  if (row < 4096){ W=Wq; rr=row; }
  else if (row < 6144){ W=Wk; rr=row-4096; }
  else { W=Wv; rr=row-6144; }
  float acc = dotrow704((const float4*)(W + (size_t)rr*D_MODEL),
                        (const float4*)sh, lane);
  if (lane==0) out[row]=acc;
}

// K2: per-head rmsnorm (+weight for q,k) then RoPE for q,k; plain rmsnorm for v
__global__ __launch_bounds__(256) void k_headnorm(const float* __restrict__ qkv,
    const float* __restrict__ qw, const float* __restrict__ kw,
    const float* __restrict__ cs, const float* __restrict__ sn,
    float* __restrict__ qf, float* __restrict__ kf, float* __restrict__ vf){
  __shared__ float sm[8];
  __shared__ float nb[DH];
  int b = blockIdx.x, t = threadIdx.x;
  const float* src; float* dst; const float* w = nullptr; bool rope=false;
  if (b < 16){ src=qkv + b*DH; dst=qf + b*DH; w=qw; rope=true; }
  else if (b < 24){ int hh=b-16; src=qkv+4096+hh*DH; dst=kf+hh*DH; w=kw; rope=true; }
  else { int hh=b-24; src=qkv+6144+hh*DH; dst=vf+hh*DH; }
  float v = src[t];
  float ss = block_sum(v*v, sm);
  float r = rsqrtf(ss/(float)DH + EPS);
  float nv = v*r*(w ? (1.f+w[t]) : 1.f);
  nb[t]=nv;
  __syncthreads();
  float o = nv;
  if (rope){
    float rot = (t < 128) ? -nb[t+128] : nb[t-128];
    o = nv*cs[t] + rot*sn[t];
  }
  dst[t]=o;
}

// K3: attn partials (blocks 0..255) + contiguous KV copy (256..2303)
#define TOT4 (NKV*MAX_CTX*(DH/4))   // 2,097,152 float4 per tensor
__global__ __launch_bounds__(256) void k_kvattn(const float* __restrict__ kc,
    const float* __restrict__ vc, const float* __restrict__ kf,
    const float* __restrict__ vf, const float* __restrict__ qf,
    const float* __restrict__ wm, const float* __restrict__ mask,
    float* __restrict__ ko, float* __restrict__ vo, float* __restrict__ part){
  int bid = blockIdx.x;
  int t = threadIdx.x;
  if (bid >= 256){
    size_t base = (size_t)(bid - 256) * 2048;
    int tensor = base >= (size_t)TOT4;
    size_t j0 = base - (tensor ? (size_t)TOT4 : 0);
    int head = (int)(j0 >> 18);
    const float4* cache = (const float4*)(tensor ? vc : kc) + j0;
    float4* outp = (float4*)(tensor ? vo : ko) + j0;
    const float4* a4 = (const float4*)((tensor ? vf : kf) + head*DH);
    float4 c[8]; float4 aq[8]; float mq[8];
    #pragma unroll
    for (int q=0;q<8;q++) c[q] = cache[q*256 + t];
    #pragma unroll
    for (int q=0;q<8;q++){
      size_t j = j0 + q*256 + t;
      aq[q] = a4[j & 63];
      mq[q] = wm[(j >> 6) & (MAX_CTX-1)];
    }
    #pragma unroll
    for (int q=0;q<8;q++){
      c[q].x = fmaf(aq[q].x, mq[q], c[q].x);
      c[q].y = fmaf(aq[q].y, mq[q], c[q].y);
      c[q].z = fmaf(aq[q].z, mq[q], c[q].z);
      c[q].w = fmaf(aq[q].w, mq[q], c[q].w);
      outp[q*256 + t] = c[q];
    }
    return;
  }
  __shared__ float sc[256];
  __shared__ float sw[256];
  __shared__ float sm[8];
  int head = bid >> 4, chunk = bid & 15;
  int kvh = head >> 1;
  int lane = t & 63, wv = t >> 6;
  int base = chunk*256;
  float mk_t = mask[base + t];
  float live = block_sum((mk_t > -1e8f) ? 1.f : 0.f, sm);
  float* p = part + (size_t)(head*16+chunk)*258;
  if (live == 0.f){
    if (t == 0){ p[0] = -3.0e38f; p[1] = 0.f; }
    return;
  }
  float4 q  = ((const float4*)(qf + head*DH))[lane];
  float4 kp = ((const float4*)(kf + kvh*DH))[lane];
  float vp  = vf[kvh*DH + t];
  const float* K = kc + (size_t)kvh*MAX_CTX*DH;
  const float* V = vc + (size_t)kvh*MAX_CTX*DH;
  for (int i=0;i<64;i++){
    int pp = wv*64 + i;
    int pos = base + pp;
    float mk = mask[pos];
    float s = -3.0e38f;
    if (mk > -1e8f){
      float m = wm[pos];
      float4 kv = ((const float4*)(K + (size_t)pos*DH))[lane];
      kv.x = fmaf(kp.x, m, kv.x); kv.y = fmaf(kp.y, m, kv.y);
      kv.z = fmaf(kp.z, m, kv.z); kv.w = fmaf(kp.w, m, kv.w);
      float d = wsum(dot4(q, kv));
      s = d + mk;
    }
    if (lane==0) sc[pp] = s;
  }
  __syncthreads();
  float sv = sc[t];
  float mx = wmax(sv);
  __syncthreads();
  if (lane==0) sm[wv]=mx;
  __syncthreads();
  mx = fmaxf(fmaxf(sm[0],sm[1]),fmaxf(sm[2],sm[3]));
  float w = (sv > -1e30f) ? __expf(sv - mx) : 0.f;
  sw[t] = w;
  float ssum = block_sum(w, sm);
  float acc = 0.f;
  for (int i=0;i<256;i++){
    float wi = sw[i];
    if (wi != 0.f){
      float v = fmaf(vp, wm[base+i], V[(size_t)(base+i)*DH + t]);
      acc = fmaf(wi, v, acc);
    }
  }
  if (t==0){ p[0]=mx; p[1]=ssum; }
  p[2+t]=acc;
}

// K4: combine partials -> ctx
__global__ __launch_bounds__(256) void k_attn_comb(const float* __restrict__ part,
    float* __restrict__ ctx){
  int head = blockIdx.x, t = threadIdx.x;
  float M = -3.0e38f;
  for (int c=0;c<16;c++) M = fmaxf(M, part[(size_t)(head*16+c)*258]);
  float tot = 0.f, acc = 0.f;
  for (int c=0;c<16;c++){
    const float* p = part + (size_t)(head*16+c)*258;
    float mc=p[0], scv=p[1];
    if (scv > 0.f){
      float f = __expf(mc - M);
      tot = fmaf(scv, f, tot);
      acc = fmaf(f, p[2+t], acc);
    }
  }
  ctx[head*DH + t] = acc / tot;
}

// K5: Wo GEMV, ctx staged in LDS, 16 batched loads
__global__ __launch_bounds__(256) void k_wo(const float* __restrict__ Wo,
    const float* __restrict__ ctxv, float* __restrict__ a){
  __shared__ float4 xs[1024];
  int t = threadIdx.x;
  #pragma unroll
  for (int i=0;i<4;i++) xs[t + 256*i] = ((const float4*)ctxv)[t + 256*i];
  __syncthreads();
  int row = blockIdx.x*4 + (t>>6);
  int lane = t & 63;
  const float4* wr = (const float4*)(Wo + (size_t)row*(H*DH));
  float4 w[16];
  #pragma unroll
  for (int i=0;i<16;i++) w[i] = wr[lane + 64*i];
  float acc = 0.f;
  #pragma unroll
  for (int i=0;i<16;i++) acc += dot4(w[i], xs[lane + 64*i]);
  acc = wsum(acc);
  if (lane==0) a[row]=acc;
}

// K6: x1 = x + rmsnorm(a, post_attn); pre/hr/pre2 = the three norms of x1
__global__ __launch_bounds__(256) void k_postattn(const float* __restrict__ a,
    const float* __restrict__ x, const float* __restrict__ wpost,
    const float* __restrict__ wpre, const float* __restrict__ rscale,
    const float* __restrict__ wpre2,
    float* __restrict__ x1, float* __restrict__ pre,
    float* __restrict__ hr, float* __restrict__ pre2){
  __shared__ float sm[8];
  int t = threadIdx.x;
  float av[11]; float ss=0.f;
  #pragma unroll
  for (int i=0;i<11;i++){ av[i]=a[t+256*i]; ss += av[i]*av[i]; }
  ss = block_sum(ss, sm);
  float ra = rsqrtf(ss/(float)D_MODEL + EPS);
  float xv[11]; float ss2=0.f;
  #pragma unroll
  for (int i=0;i<11;i++){
    int idx=t+256*i;
    xv[i] = x[idx] + av[i]*ra*(1.f+wpost[idx]);
    ss2 += xv[i]*xv[i];
  }
  ss2 = block_sum(ss2, sm);
  float r1 = rsqrtf(ss2/(float)D_MODEL + EPS);
  const float invsq = rsqrtf((float)D_MODEL);
  #pragma unroll
  for (int i=0;i<11;i++){
    int idx=t+256*i;
    float n = xv[i]*r1;
    x1[idx]=xv[i];
    pre[idx]=n*(1.f+wpre[idx]);
    hr[idx]=n*rscale[idx]*invsq;
    pre2[idx]=n*(1.f+wpre2[idx]);
  }
}

// K7: dense gate/up (0..527) + router logits (528..559)
__global__ __launch_bounds__(256) void k_dense_gu_router(const float* __restrict__ Wg,
    const float* __restrict__ Wu, const float* __restrict__ pre,
    const float* __restrict__ Wp, const float* __restrict__ hr,
    float* __restrict__ act, float* __restrict__ lg){
  __shared__ float4 xs[DM4];
  int t = threadIdx.x;
  int lane = t & 63, wv = t >> 6;
  bool isdense = (blockIdx.x < 528);
  const float4* src = (const float4*)(isdense ? pre : hr);
  xs[t] = src[t];
  xs[t+256] = src[t+256];
  if (t < 192) xs[t+512] = src[t+512];
  __syncthreads();
  if (isdense){
    int row = blockIdx.x*4 + wv;
    const float4* g4 = (const float4*)(Wg + (size_t)row*D_MODEL);
    const float4* u4 = (const float4*)(Wu + (size_t)row*D_MODEL);
    float4 g[11], u[11];
    #pragma unroll
    for (int i=0;i<11;i++) g[i] = g4[lane + 64*i];
    #pragma unroll
    for (int i=0;i<11;i++) u[i] = u4[lane + 64*i];
    float ag=0.f, au=0.f;
    #pragma unroll
    for (int i=0;i<11;i++){
      float4 b = xs[lane + 64*i];
      ag += dot4(g[i], b);
      au += dot4(u[i], b);
    }
    ag = wsum(ag); au = wsum(au);
    if (lane==0) act[row] = gelu_tanh(ag)*au;
  } else {
    int row = (blockIdx.x-528)*4 + wv;
    float acc = dotrow704((const float4*)(Wp + (size_t)row*D_MODEL), xs, lane);
    if (lane==0) lg[row]=acc;
  }
}

// K8: softmax + top-8 (1 wave)
__global__ __launch_bounds__(64) void k_topk(const float* __restrict__ lg,
    const float* __restrict__ pes, float* __restrict__ selw, int* __restrict__ seli){
  int lane = threadIdx.x;
  float l0 = lg[lane], l1 = lg[lane+64];
  float m = wmax_all(fmaxf(l0,l1));
  float e0 = __expf(l0-m), e1 = __expf(l1-m);
  float s = wsum_all(e0+e1);
  float p0 = e0/s, p1 = e1/s;
  float vals[8]; int idxs[8]; float tw=0.f;
  #pragma unroll
  for (int ts=0;ts<8;ts++){
    float mx = wmax_all(fmaxf(p0,p1));
    int cand = 0x7fffffff;
    if (p0 == mx) cand = lane;
    else if (p1 == mx) cand = lane + 64;
    int imin = wmin_all_i(cand);
    if (imin == lane) p0 = -1.f;
    else if (imin == lane+64) p1 = -1.f;
    vals[ts]=mx; idxs[ts]=imin; tw += mx;
  }
  if (lane == 0){
    #pragma unroll
    for (int ts=0;ts<8;ts++){
      selw[ts] = vals[ts]/tw*pes[idxs[ts]];
      seli[ts] = idxs[ts];
    }
  }
}

// K9: dense down-proj (0..703) + MoE gate/up (704..2111)
__global__ __launch_bounds__(256) void k_ddown_moegu(const float* __restrict__ Wd,
    const float* __restrict__ act, float* __restrict__ dense,
    const float* __restrict__ pWg, const float* __restrict__ pWu,
    const float* __restrict__ pre2, const int* __restrict__ seli,
    float* __restrict__ hh){
  __shared__ float4 xs[DM4];
  int t = threadIdx.x;
  int lane = t & 63, wv = t >> 6;
  if (blockIdx.x < 704){
    xs[t] = ((const float4*)act)[t];
    xs[t+256] = ((const float4*)act)[t+256];
    if (t < 16) xs[t+512] = ((const float4*)act)[t+512];
    __syncthreads();
    int row = blockIdx.x*4 + wv;
    const float4* wr = (const float4*)(Wd + (size_t)row*D_DENSE);
    float4 w[8];
    #pragma unroll
    for (int i=0;i<8;i++) w[i] = wr[lane + 64*i];
    float4 w8 = (lane < 16) ? wr[lane + 512] : make_float4(0.f,0.f,0.f,0.f);
    float acc = 0.f;
    #pragma unroll
    for (int i=0;i<8;i++) acc += dot4(w[i], xs[lane + 64*i]);
    if (lane < 16) acc += dot4(w8, xs[lane + 512]);
    acc = wsum(acc);
    if (lane==0) dense[row]=acc;
  } else {
    xs[t] = ((const float4*)pre2)[t];
    xs[t+256] = ((const float4*)pre2)[t+256];
    if (t < 192) xs[t+512] = ((const float4*)pre2)[t+512];
    __syncthreads();
    int gidx = (blockIdx.x-704)*4 + wv;
    int sl = gidx / D_FFN;
    int f = gidx - sl*D_FFN;
    int e = seli[sl];
    int p = e >> 4, g = e & 15;
    size_t ro = ((size_t)p*(16*D_FFN) + (size_t)g*D_FFN + f)*D_MODEL;
    const float4* g4 = (const float4*)(pWg + ro);
    const float4* u4 = (const float4*)(pWu + ro);
    float4 gw[11], uw[11];
    #pragma unroll
    for (int i=0;i<11;i++) gw[i] = g4[lane + 64*i];
    #pragma unroll
    for (int i=0;i<11;i++) uw[i] = u4[lane + 64*i];
    float ag=0.f, au=0.f;
    #pragma unroll
    for (int i=0;i<11;i++){
      float4 b = xs[lane + 64*i];
      ag += dot4(gw[i], b);
      au += dot4(uw[i], b);
    }
    ag = wsum(ag); au = wsum(au);
    if (lane==0) hh[sl*D_FFN + f] = gelu_tanh(ag)*au;
  }
}

// K10: MoE down-proj
__global__ __launch_bounds__(256) void k_moe_down(const float* __restrict__ Wd,
    const float* __restrict__ hh, const int* __restrict__ seli,
    float* __restrict__ pere){
  __shared__ float4 xs[DF4];
  int t = threadIdx.x;
  int gidx = blockIdx.x*4 + (t>>6);
  int lane = t & 63;
  int sl = gidx / D_MODEL;
  int d = gidx - sl*D_MODEL;
  if (t < DF4) xs[t] = ((const float4*)(hh + sl*D_FFN))[t];
  __syncthreads();
  int e = seli[sl];
  int p = e >> 4, g = e & 15;
  const float4* wr = (const float4*)(Wd + ((size_t)p*(16*D_MODEL) + (size_t)g*D_MODEL + d)*D_FFN);
  float4 w0 = wr[lane];
  float4 w1 = wr[lane + 64];
  float4 w2 = (lane < 48) ? wr[lane + 128] : make_float4(0.f,0.f,0.f,0.f);
  float acc = dot4(w0, xs[lane]) + dot4(w1, xs[lane + 64]);
  if (lane < 48) acc += dot4(w2, xs[lane + 128]);
  acc = wsum(acc);
  if (lane==0) pere[sl*D_MODEL + d] = acc;
}

// K11: final combine
__global__ __launch_bounds__(256) void k_final(const float* __restrict__ pere,
    const float* __restrict__ selw, const float* __restrict__ dense,
    const float* __restrict__ x1, const float* __restrict__ w2,
    const float* __restrict__ w1, const float* __restrict__ wf,
    const float* __restrict__ lsc, float* __restrict__ out){
  __shared__ float sm[8];
  int t = threadIdx.x;
  float mo[11], dn[11]; float ssm_=0.f, ssd=0.f;
  #pragma unroll
  for (int i=0;i<11;i++){
    int idx=t+256*i;
    float mv=0.f;
    #pragma unroll
    for (int s=0;s<TOPK;s++) mv = fmaf(selw[s], pere[s*D_MODEL+idx], mv);
    mo[i]=mv; ssm_ += mv*mv;
    dn[i]=dense[idx]; ssd += dn[i]*dn[i];
  }
  ssm_ = block_sum(ssm_, sm);
  ssd = block_sum(ssd, sm);
  float rm = rsqrtf(ssm_/(float)D_MODEL + EPS);
  float rd = rsqrtf(ssd/(float)D_MODEL + EPS);
  float tv[11]; float sst=0.f;
  #pragma unroll
  for (int i=0;i<11;i++){
    int idx=t+256*i;
    float h2 = mo[i]*rm*(1.f+w2[idx]);
    float h1 = dn[i]*rd*(1.f+w1[idx]);
    tv[i]=h1+h2; sst += tv[i]*tv[i];
  }
  sst = block_sum(sst, sm);
  float rt = rsqrtf(sst/(float)D_MODEL + EPS);
  float l = lsc[0];
  #pragma unroll
  for (int i=0;i<11;i++){
    int idx=t+256*i;
    out[idx] = (x1[idx] + tv[i]*rt*(1.f+wf[idx]))*l;
  }
}

extern "C" void kernel_launch(void* const* d_in, const int* in_sizes, int n_in,
                              void* d_out, int out_size, void* d_ws, size_t ws_size,
                              hipStream_t stream){
  const float* x        = (const float*)d_in[0];
  const float* cs       = (const float*)d_in[1];
  const float* sn       = (const float*)d_in[2];
  const float* kc       = (const float*)d_in[3];
  const float* vc       = (const float*)d_in[4];
  const float* mask     = (const float*)d_in[5];
  const float* wm       = (const float*)d_in[6];
  const float* in_ln    = (const float*)d_in[7];
  const float* post_attn= (const float*)d_in[8];
  const float* pre_ffn  = (const float*)d_in[9];
  const float* post_ffn1= (const float*)d_in[10];
  const float* pre_ffn2 = (const float*)d_in[11];
  const float* post_ffn2= (const float*)d_in[12];
  const float* post_ffn = (const float*)d_in[13];
  const float* Wq       = (const float*)d_in[14];
  const float* Wk       = (const float*)d_in[15];
  const float* Wv       = (const float*)d_in[16];
  const float* Wo       = (const float*)d_in[17];
  const float* qnw      = (const float*)d_in[18];
  const float* knw      = (const float*)d_in[19];
  const float* dWg      = (const float*)d_in[20];
  const float* dWu      = (const float*)d_in[21];
  const float* dWd      = (const float*)d_in[22];
  const float* rWp      = (const float*)d_in[23];
  const float* rscale   = (const float*)d_in[24];
  const float* rpes     = (const float*)d_in[25];
  const float* pWg      = (const float*)d_in[26];
  const float* pWu      = (const float*)d_in[27];
  const float* pWd      = (const float*)d_in[28];
  const float* lsc      = (const float*)d_in[29];

  float* out = (float*)d_out;
  float* ko  = out + D_MODEL;
  float* vo  = ko + (size_t)NKV*MAX_CTX*DH;

  float* ws   = (float*)d_ws;
  float* qkv  = ws + 0;        // 8192
  float* qf   = ws + 8192;     // 4096
  float* kf   = ws + 12288;    // 2048
  float* vf   = ws + 14336;    // 2048
  float* ctx  = ws + 16384;    // 4096
  float* a    = ws + 20480;    // 2816
  float* x1   = ws + 23296;    // 2816
  float* pre  = ws + 26112;    // 2816
  float* hr   = ws + 28928;    // 2816
  float* pre2 = ws + 31744;    // 2816
  float* act  = ws + 34560;    // 2112
  float* dense= ws + 36672;    // 2816
  float* lg   = ws + 39488;    // 128
  float* selw = ws + 39616;    // 8
  int*   seli = (int*)(ws + 39624); // 8
  float* hh   = ws + 39632;    // 8*704 = 5632
  float* pere = ws + 45264;    // 8*2816 = 22528
  float* part = ws + 67792;    // 16*16*258 = 66048

  k_qkv            <<<2048, 256, 0, stream>>>(Wq, Wk, Wv, x, in_ln, qkv);
  k_headnorm       <<<32,   256, 0, stream>>>(qkv, qnw, knw, cs, sn, qf, kf, vf);
  k_kvattn         <<<2304, 256, 0, stream>>>(kc, vc, kf, vf, qf, wm, mask, ko, vo, part);
  k_attn_comb      <<<16,   256, 0, stream>>>(part, ctx);
  k_wo             <<<704,  256, 0, stream>>>(Wo, ctx, a);
  k_postattn       <<<1,    256, 0, stream>>>(a, x, post_attn, pre_ffn, rscale, pre_ffn2,
                                              x1, pre, hr, pre2);
  k_dense_gu_router<<<560,  256, 0, stream>>>(dWg, dWu, pre, rWp, hr, act, lg);
  k_topk           <<<1,     64, 0, stream>>>(lg, rpes, selw, seli);
  k_ddown_moegu    <<<2112, 256, 0, stream>>>(dWd, act, dense, pWg, pWu, pre2, seli, hh);
  k_moe_down       <<<5632, 256, 0, stream>>>(pWd, hh, seli, pere);
  k_final          <<<1,    256, 0, stream>>>(pere, selw, dense, x1,
                                              post_ffn2, post_ffn1, post_ffn, lsc, out);
}